// Round 5
// baseline (375.949 us; speedup 1.0000x reference)
//
#include <hip/hip_runtime.h>
#include <stdint.h>
#include <math.h>

#define S_LEN 2048
#define HID 2048
#define NH 16
#define HD 128
#define NROWS 4096  // B*S
#define SCALE 0.08838834764831845f
#define C2 (0.08838834764831845f * 1.442695040888963f)  // SCALE * log2(e)

typedef unsigned short u16;
typedef __attribute__((ext_vector_type(8))) short short8;
typedef __attribute__((ext_vector_type(4))) float f32x4;
typedef __attribute__((ext_vector_type(16))) float f32x16;
typedef __attribute__((ext_vector_type(4))) unsigned short u16x4;
typedef __attribute__((ext_vector_type(4))) unsigned int u32x4;
typedef __attribute__((ext_vector_type(4))) float float4v;

__device__ __forceinline__ u16 f2bf(float f) {
  union { float f; uint32_t u; } v; v.f = f;
  uint32_t r = v.u + 0x7FFFu + ((v.u >> 16) & 1u);
  return (u16)(r >> 16);
}
__device__ __forceinline__ float bf2f(u16 b) {
  union { uint32_t u; float f; } v; v.u = ((uint32_t)b) << 16;
  return v.f;
}
__device__ __forceinline__ void gl_lds16(const void* g, void* l) {
  __builtin_amdgcn_global_load_lds((const __attribute__((address_space(1))) void*)g,
                                   (__attribute__((address_space(3))) void*)l, 16, 0, 0);
}
__device__ __forceinline__ unsigned cvtpk(float lo, float hi) {
  unsigned r;
  asm("v_cvt_pk_bf16_f32 %0, %1, %2" : "=v"(r) : "v"(lo), "v"(hi));
  return r;
}
__device__ __forceinline__ void plswap(unsigned &a, unsigned &b) {
  asm volatile("v_permlane32_swap_b32 %0, %1" : "+v"(a), "+v"(b));
}

// ---------------- RMSNorm: x (f32 [4096][2048]) -> xn (bf16) ----------------
__global__ __launch_bounds__(256) void k_rmsnorm(const float* __restrict__ x,
                                                 const float* __restrict__ w,
                                                 u16* __restrict__ xn) {
  int row = blockIdx.x;
  int tid = threadIdx.x;
  const float* xr = x + (size_t)row * HID;
  float4v a = *(const float4v*)(xr + tid * 8);
  float4v b = *(const float4v*)(xr + tid * 8 + 4);
  float s = a[0]*a[0] + a[1]*a[1] + a[2]*a[2] + a[3]*a[3]
          + b[0]*b[0] + b[1]*b[1] + b[2]*b[2] + b[3]*b[3];
  #pragma unroll
  for (int off = 1; off < 64; off <<= 1) s += __shfl_xor(s, off, 64);
  __shared__ float red[4];
  int wv = tid >> 6;
  if ((tid & 63) == 0) red[wv] = s;
  __syncthreads();
  float tot = red[0] + red[1] + red[2] + red[3];
  float r = rsqrtf(tot * (1.0f / HID) + 1e-5f);
  const float* wp = w + tid * 8;
  u16x4 o0, o1;
  #pragma unroll
  for (int j = 0; j < 4; ++j) { o0[j] = f2bf(a[j] * r * wp[j]); o1[j] = f2bf(b[j] * r * wp[4 + j]); }
  *(u16x4*)(xn + (size_t)row * HID + tid * 8) = o0;
  *(u16x4*)(xn + (size_t)row * HID + tid * 8 + 4) = o1;
}

// ---------- weight transpose+convert (all 4): w f32 [K][N] -> wt bf16 [N][K] ----------
__global__ __launch_bounds__(256) void k_wconv4(const float* __restrict__ w0, const float* __restrict__ w1,
                                                const float* __restrict__ w2, const float* __restrict__ w3,
                                                u16* __restrict__ wtbase) {
  int z = blockIdx.z;
  const float* w = (z == 0) ? w0 : (z == 1) ? w1 : (z == 2) ? w2 : w3;
  u16* wt = wtbase + (size_t)z * HID * HID;
  int n0 = blockIdx.x * 64, k0 = blockIdx.y * 64;
  __shared__ float t[64][68];
  int tid = threadIdx.x;
  int cr = tid >> 4;
  int cc = (tid & 15) * 4;
  #pragma unroll
  for (int it = 0; it < 4; ++it) {
    int kk = cr + it * 16;
    float4v v = *(const float4v*)(w + (size_t)(k0 + kk) * HID + n0 + cc);
    t[kk][cc] = v[0]; t[kk][cc + 1] = v[1]; t[kk][cc + 2] = v[2]; t[kk][cc + 3] = v[3];
  }
  __syncthreads();
  #pragma unroll
  for (int it = 0; it < 4; ++it) {
    int nn = cr + it * 16;
    u16x4 o;
    #pragma unroll
    for (int j = 0; j < 4; ++j) o[j] = f2bf(t[cc + j][nn]);
    *(u16x4*)(wt + (size_t)(n0 + nn) * HID + k0 + cc) = o;
  }
}

// ---------- v transpose: vh bf16 [bh][s][d] -> vt bf16 [bh*128+d][s] ----------
__global__ __launch_bounds__(256) void k_vtrans(const u16* __restrict__ v, u16* __restrict__ vt) {
  int s0 = blockIdx.x * 64;
  int d0 = blockIdx.y * 64;
  int bh = blockIdx.z;
  __shared__ u16 t[64][68];
  int tid = threadIdx.x;
  int cr = tid >> 4;
  int cc = (tid & 15) * 4;
  #pragma unroll
  for (int it = 0; it < 4; ++it) {
    int ss = cr + it * 16;
    u16x4 vv = *(const u16x4*)(v + ((size_t)(bh * S_LEN + s0 + ss)) * HD + d0 + cc);
    t[ss][cc] = vv[0]; t[ss][cc + 1] = vv[1]; t[ss][cc + 2] = vv[2]; t[ss][cc + 3] = vv[3];
  }
  __syncthreads();
  #pragma unroll
  for (int it = 0; it < 4; ++it) {
    int dd = cr + it * 16;
    u16x4 o;
    #pragma unroll
    for (int j = 0; j < 4; ++j) o[j] = t[cc + j][dd];
    *(u16x4*)(vt + ((size_t)(bh * HD) + d0 + dd) * S_LEN + s0 + cc) = o;
  }
}

// ---------- RoPE in-place on q and k (head-major [bh][s][d]) ----------
__global__ __launch_bounds__(256) void k_rope(u16* __restrict__ q, u16* __restrict__ k) {
  int gid = blockIdx.x * 256 + threadIdx.x;
  int row = gid >> 6;           // bh*2048 + s, over 65536 rows
  int p = gid & 63;             // pair index
  int s = row & (S_LEN - 1);
  size_t base = (size_t)row * HD;
  float freq = exp2f((float)p * -0.20762050593046014f);  // theta^(-p/64)
  float ang = (float)s * freq;
  float sn, cs;
  sincosf(ang, &sn, &cs);
  {
    float x0 = bf2f(q[base + 2 * p]), x1 = bf2f(q[base + 2 * p + 1]);
    float val = (p & 1) ? (sn * x0 + cs * x1) : (cs * x0 - sn * x1);
    u16 bvv = f2bf(val);
    q[base + p] = bvv; q[base + p + 64] = bvv;
  }
  {
    float x0 = bf2f(k[base + 2 * p]), x1 = bf2f(k[base + 2 * p + 1]);
    float val = (p & 1) ? (sn * x0 + cs * x1) : (cs * x0 - sn * x1);
    u16 bvv = f2bf(val);
    k[base + p] = bvv; k[base + p + 64] = bvv;
  }
}

// ---------- fused QKV GEMM: C[M=4096][N=6144] = A bf16 [M][K] * BT bf16 [N][K] ----------
// outputs head-major: sel-buffer[((b*16+h)*2048 + s)*128 + d]
__global__ __launch_bounds__(256) void k_gemm_qkv(const u16* __restrict__ A, const u16* __restrict__ BT,
                                                  const float* __restrict__ bq, const float* __restrict__ bk,
                                                  const float* __restrict__ bv, u16* __restrict__ qkv) {
  __shared__ __align__(16) u16 lA[128 * 64];
  __shared__ __align__(16) u16 lB[128 * 64];
  int bx = blockIdx.x, by = blockIdx.y;
  int sel = bx >> 4;
  const float* bias = (sel == 0) ? bq : (sel == 1) ? bk : bv;
  u16* outp = qkv + (size_t)sel * NROWS * HID;
  int tid = threadIdx.x;
  int wv = tid >> 6, lane = tid & 63;
  int wr = wv >> 1, wc = wv & 1;
  int lq = lane & 15, lg = lane >> 4;
  f32x4 acc[4][4];
  #pragma unroll
  for (int mi = 0; mi < 4; ++mi)
    #pragma unroll
    for (int ni = 0; ni < 4; ++ni) acc[mi][ni] = (f32x4){0.f, 0.f, 0.f, 0.f};

  const size_t Abase = (size_t)(by * 128) * HID;
  const size_t Bbase = (size_t)(bx * 128) * HID;
  for (int k0 = 0; k0 < HID; k0 += 64) {
    __syncthreads();
    #pragma unroll
    for (int it = 0; it < 4; ++it) {
      int c = it * 256 + tid;
      int row = c >> 3;
      int cir = (c & 7) ^ (row & 7);
      gl_lds16(A + Abase + (size_t)row * HID + k0 + cir * 8, lA + (it * 256 + wv * 64) * 8);
    }
    #pragma unroll
    for (int it = 0; it < 4; ++it) {
      int c = it * 256 + tid;
      int row = c >> 3;
      int cir = (c & 7) ^ (row & 7);
      gl_lds16(BT + Bbase + (size_t)row * HID + k0 + cir * 8, lB + (it * 256 + wv * 64) * 8);
    }
    __syncthreads();
    #pragma unroll
    for (int kk = 0; kk < 2; ++kk) {
      int ch = kk * 4 + lg;
      short8 afr[4], bfr[4];
      #pragma unroll
      for (int mi = 0; mi < 4; ++mi) {
        int r = wr * 64 + mi * 16 + lq;
        afr[mi] = *(const short8*)(lA + r * 64 + ((ch ^ (r & 7)) << 3));
      }
      #pragma unroll
      for (int ni = 0; ni < 4; ++ni) {
        int r = wc * 64 + ni * 16 + lq;
        bfr[ni] = *(const short8*)(lB + r * 64 + ((ch ^ (r & 7)) << 3));
      }
      #pragma unroll
      for (int mi = 0; mi < 4; ++mi)
        #pragma unroll
        for (int ni = 0; ni < 4; ++ni)
          acc[mi][ni] = __builtin_amdgcn_mfma_f32_16x16x32_bf16(afr[mi], bfr[ni], acc[mi][ni], 0, 0, 0);
    }
  }
  #pragma unroll
  for (int ni = 0; ni < 4; ++ni) {
    int colg = bx * 128 + wc * 64 + ni * 16 + lq;
    int col = colg & 2047;
    int h = col >> 7, d = col & 127;
    float bs = bias[col];
    #pragma unroll
    for (int mi = 0; mi < 4; ++mi) {
      #pragma unroll
      for (int r = 0; r < 4; ++r) {
        int rowm = by * 128 + wr * 64 + mi * 16 + lg * 4 + r;
        int b = rowm >> 11, s = rowm & 2047;
        outp[(((size_t)(b * NH + h)) * S_LEN + s) * HD + d] = f2bf(acc[mi][ni][r] + bs);
      }
    }
  }
}

// ---------- output GEMM: C[M=4096][N=2048] f32 = A*BT + bias + resid ----------
__global__ __launch_bounds__(256) void k_gemm_o(const u16* __restrict__ A, const u16* __restrict__ BT,
                                                const float* __restrict__ bias,
                                                const float* __restrict__ resid,
                                                float* __restrict__ outp) {
  __shared__ __align__(16) u16 lA[128 * 64];
  __shared__ __align__(16) u16 lB[128 * 64];
  int bx = blockIdx.x, by = blockIdx.y;
  int tid = threadIdx.x;
  int wv = tid >> 6, lane = tid & 63;
  int wr = wv >> 1, wc = wv & 1;
  int lq = lane & 15, lg = lane >> 4;
  f32x4 acc[4][4];
  #pragma unroll
  for (int mi = 0; mi < 4; ++mi)
    #pragma unroll
    for (int ni = 0; ni < 4; ++ni) acc[mi][ni] = (f32x4){0.f, 0.f, 0.f, 0.f};

  const size_t Abase = (size_t)(by * 128) * HID;
  const size_t Bbase = (size_t)(bx * 128) * HID;
  for (int k0 = 0; k0 < HID; k0 += 64) {
    __syncthreads();
    #pragma unroll
    for (int it = 0; it < 4; ++it) {
      int c = it * 256 + tid;
      int row = c >> 3;
      int cir = (c & 7) ^ (row & 7);
      gl_lds16(A + Abase + (size_t)row * HID + k0 + cir * 8, lA + (it * 256 + wv * 64) * 8);
    }
    #pragma unroll
    for (int it = 0; it < 4; ++it) {
      int c = it * 256 + tid;
      int row = c >> 3;
      int cir = (c & 7) ^ (row & 7);
      gl_lds16(BT + Bbase + (size_t)row * HID + k0 + cir * 8, lB + (it * 256 + wv * 64) * 8);
    }
    __syncthreads();
    #pragma unroll
    for (int kk = 0; kk < 2; ++kk) {
      int ch = kk * 4 + lg;
      short8 afr[4], bfr[4];
      #pragma unroll
      for (int mi = 0; mi < 4; ++mi) {
        int r = wr * 64 + mi * 16 + lq;
        afr[mi] = *(const short8*)(lA + r * 64 + ((ch ^ (r & 7)) << 3));
      }
      #pragma unroll
      for (int ni = 0; ni < 4; ++ni) {
        int r = wc * 64 + ni * 16 + lq;
        bfr[ni] = *(const short8*)(lB + r * 64 + ((ch ^ (r & 7)) << 3));
      }
      #pragma unroll
      for (int mi = 0; mi < 4; ++mi)
        #pragma unroll
        for (int ni = 0; ni < 4; ++ni)
          acc[mi][ni] = __builtin_amdgcn_mfma_f32_16x16x32_bf16(afr[mi], bfr[ni], acc[mi][ni], 0, 0, 0);
    }
  }
  #pragma unroll
  for (int ni = 0; ni < 4; ++ni) {
    int col = bx * 128 + wc * 64 + ni * 16 + lq;
    float bs = bias[col];
    #pragma unroll
    for (int mi = 0; mi < 4; ++mi) {
      #pragma unroll
      for (int r = 0; r < 4; ++r) {
        int rowm = by * 128 + wr * 64 + mi * 16 + lg * 4 + r;
        size_t o = (size_t)rowm * HID + col;
        outp[o] = acc[mi][ni][r] + bs + resid[o];
      }
    }
  }
}

// ---------- flash attention v4: barrier-free, LDS-free, per-wave 32 q-rows, 32x32x16 MFMA ----------
// qh,kh bf16 [bh][s][d] (rope'd head-major), vt bf16 [bh*128+d][s], out bf16 [b][s][h*128+d]
__global__ __launch_bounds__(256, 2) void k_attn(const u16* __restrict__ qh, const u16* __restrict__ kh,
                                                 const u16* __restrict__ vt, u16* __restrict__ out) {
  int bid = blockIdx.x;           // 512 blocks
  int sub = bid >> 3;
  int bh = (bid & 7) * 4 + (sub & 3);   // 4 heads per XCD for L2 locality
  int qt = 15 - (sub >> 2);
  int b = bh >> 4, h = bh & 15;
  int tid = threadIdx.x, wv = tid >> 6, lane = tid & 63;
  int hi = lane >> 5, ln = lane & 31;
  int q0 = qt * 128 + wv * 32;
  int qrow = q0 + ln;             // this lane's q (S^T col, O^T col)

  // Q B-frags: B[k=d][n=q], k = 16*ks + 8*hi + j
  const u16* qbase = qh + ((size_t)bh * S_LEN + qrow) * HD + hi * 8;
  short8 qf[8];
  #pragma unroll
  for (int ks = 0; ks < 8; ++ks) qf[ks] = *(const short8*)(qbase + ks * 16);

  f32x16 oc[4];   // O^T[d=db*32+crow(r,hi)][q=ln]
  #pragma unroll
  for (int db = 0; db < 4; ++db)
    #pragma unroll
    for (int r = 0; r < 16; ++r) oc[db][r] = 0.f;
  float mr = -3.0e38f, l = 0.f;

  const u16* krow = kh + ((size_t)bh * S_LEN + ln) * HD + hi * 8;
  const u16* vrow = vt + ((size_t)(bh * HD) + ln) * S_LEN + hi * 8;

  int ntile = qt * 4 + wv + 1;    // 32-key tiles, t <= q0+31
  for (int tt = 0; tt < ntile; ++tt) {
    int t0 = tt * 32;
    // K A-frags: A[m=t0+ln][k=d=16ks+8hi+j]
    short8 kf[8];
    #pragma unroll
    for (int ks = 0; ks < 8; ++ks)
      kf[ks] = *(const short8*)(krow + (size_t)t0 * HD + ks * 16);
    // V^T A-frags: A[m=d=db*32+ln][k=t=t0+16ks+8hi+j]
    short8 va[2][4];
    #pragma unroll
    for (int db = 0; db < 4; ++db) {
      va[0][db] = *(const short8*)(vrow + (size_t)(db * 32) * S_LEN + t0);
      va[1][db] = *(const short8*)(vrow + (size_t)(db * 32) * S_LEN + t0 + 16);
    }

    // S^T[t][q] = K · Q  (rows t = crow(r,hi), col q = ln)
    f32x16 st;
    #pragma unroll
    for (int r = 0; r < 16; ++r) st[r] = 0.f;
    __builtin_amdgcn_s_setprio(1);
    #pragma unroll
    for (int ks = 0; ks < 8; ++ks)
      st = __builtin_amdgcn_mfma_f32_32x32x16_bf16(kf[ks], qf[ks], st, 0, 0, 0);
    __builtin_amdgcn_s_setprio(0);

    // causal mask (only the wave's last tile can cross the diagonal)
    float sv[16];
    float pm = -3.0e38f;
    bool lastt = (tt == ntile - 1);
    #pragma unroll
    for (int r = 0; r < 16; ++r) {
      float x = st[r];
      if (lastt) {
        int t = t0 + (r & 3) + 8 * (r >> 2) + 4 * hi;
        x = (t <= qrow) ? x : -3.0e38f;
      }
      sv[r] = x;
      pm = fmaxf(pm, x);
    }
    pm = fmaxf(pm, __shfl_xor(pm, 32, 64));
    // defer-rescale (T13): rescale only when raw max grows > 64 (~e^5.7 scaled)
    if (!__all(pm <= mr + 64.0f)) {
      float mnew = fmaxf(mr, pm);
      float al = exp2f((mr - mnew) * C2);
      l *= al;
      #pragma unroll
      for (int db = 0; db < 4; ++db)
        #pragma unroll
        for (int r = 0; r < 16; ++r) oc[db][r] *= al;
      mr = mnew;
    }
    float mc = mr * C2;
    float e[16];
    float rs = 0.f;
    #pragma unroll
    for (int r = 0; r < 16; ++r) {
      e[r] = exp2f(fmaf(sv[r], C2, -mc));
      rs += e[r];
    }
    rs += __shfl_xor(rs, 32, 64);
    l += rs;

    // P -> bf16 B-frags in-register: cvt_pk pairs + permlane32_swap (T12)
    unsigned w0 = cvtpk(e[0], e[1]),  w1 = cvtpk(e[2], e[3]);
    unsigned w2 = cvtpk(e[4], e[5]),  w3 = cvtpk(e[6], e[7]);
    unsigned w4 = cvtpk(e[8], e[9]),  w5 = cvtpk(e[10], e[11]);
    unsigned w6 = cvtpk(e[12], e[13]), w7 = cvtpk(e[14], e[15]);
    plswap(w0, w2); plswap(w1, w3); plswap(w4, w6); plswap(w5, w7);
    u32x4 pw0 = {w0, w1, w2, w3};
    u32x4 pw1 = {w4, w5, w6, w7};
    short8 pb0 = __builtin_bit_cast(short8, pw0);
    short8 pb1 = __builtin_bit_cast(short8, pw1);

    // O^T += V^T · P
    __builtin_amdgcn_s_setprio(1);
    #pragma unroll
    for (int db = 0; db < 4; ++db)
      oc[db] = __builtin_amdgcn_mfma_f32_32x32x16_bf16(va[0][db], pb0, oc[db], 0, 0, 0);
    #pragma unroll
    for (int db = 0; db < 4; ++db)
      oc[db] = __builtin_amdgcn_mfma_f32_32x32x16_bf16(va[1][db], pb1, oc[db], 0, 0, 0);
    __builtin_amdgcn_s_setprio(0);
  }

  // epilogue: out[b][s=qrow][h*128 + d], d = db*32 + 8g + 4hi + j
  float inv = 1.0f / l;
  size_t ob = ((size_t)(b * S_LEN + qrow)) * HID + h * HD;
  #pragma unroll
  for (int db = 0; db < 4; ++db) {
    #pragma unroll
    for (int g = 0; g < 4; ++g) {
      u16x4 pk;
      #pragma unroll
      for (int j = 0; j < 4; ++j) pk[j] = f2bf(oc[db][4 * g + j] * inv);
      *(u16x4*)(out + ob + db * 32 + 8 * g + 4 * hi) = pk;
    }
  }
}

extern "C" void kernel_launch(void* const* d_in, const int* in_sizes, int n_in,
                              void* d_out, int out_size, void* d_ws, size_t ws_size,
                              hipStream_t stream) {
  const float* x    = (const float*)d_in[0];
  const float* rmsw = (const float*)d_in[1];
  const float* wq   = (const float*)d_in[2];
  const float* bq   = (const float*)d_in[3];
  const float* wk   = (const float*)d_in[4];
  const float* bk   = (const float*)d_in[5];
  const float* wv   = (const float*)d_in[6];
  const float* bv   = (const float*)d_in[7];
  const float* wo   = (const float*)d_in[8];
  const float* bo   = (const float*)d_in[9];

  char* ws = (char*)d_ws;
  const size_t SZ = (size_t)NROWS * HID * 2;  // bf16 activation bytes
  const size_t WSZ = (size_t)HID * HID * 2;   // bf16 weight bytes
  u16* xn   = (u16*)(ws);
  u16* wqkT = (u16*)(ws + SZ);                // wq|wk|wv|wo transposed, contiguous
  u16* woT  = (u16*)(ws + SZ + 3 * WSZ);
  u16* qhb  = (u16*)(ws + SZ + 4 * WSZ);      // q|k|v head-major, contiguous
  u16* khb  = (u16*)(ws + SZ + 4 * WSZ + SZ);
  u16* vhb  = (u16*)(ws + SZ + 4 * WSZ + 2 * SZ);
  u16* vT   = xn;   // xn dead after QKV GEMM
  u16* ao   = vhb;  // vh dead after transpose

  k_rmsnorm<<<dim3(NROWS), dim3(256), 0, stream>>>(x, rmsw, xn);
  k_wconv4<<<dim3(32, 32, 4), dim3(256), 0, stream>>>(wq, wk, wv, wo, wqkT);
  k_gemm_qkv<<<dim3(48, 32), dim3(256), 0, stream>>>(xn, wqkT, bq, bk, bv, qhb);
  k_rope<<<dim3(16384), dim3(256), 0, stream>>>(qhb, khb);
  k_vtrans<<<dim3(32, 2, 32), dim3(256), 0, stream>>>(vhb, vT);
  k_attn<<<dim3(512), dim3(256), 0, stream>>>(qhb, khb, vT, ao);
  k_gemm_o<<<dim3(16, 32), dim3(256), 0, stream>>>(ao, woT, bo, x, (float*)d_out);
}

// Round 6
// 346.846 us; speedup vs baseline: 1.0839x; 1.0839x over previous
//
#include <hip/hip_runtime.h>
#include <stdint.h>
#include <math.h>

#define S_LEN 2048
#define HID 2048
#define NH 16
#define HD 128
#define NROWS 4096  // B*S
#define SCALE 0.08838834764831845f
#define C2 (0.08838834764831845f * 1.442695040888963f)  // SCALE * log2(e)

typedef unsigned short u16;
typedef __attribute__((ext_vector_type(8))) short short8;
typedef __attribute__((ext_vector_type(4))) float f32x4;
typedef __attribute__((ext_vector_type(4))) unsigned short u16x4;
typedef __attribute__((ext_vector_type(4))) float float4v;

__device__ __forceinline__ u16 f2bf(float f) {
  union { float f; uint32_t u; } v; v.f = f;
  uint32_t r = v.u + 0x7FFFu + ((v.u >> 16) & 1u);
  return (u16)(r >> 16);
}
__device__ __forceinline__ float bf2f(u16 b) {
  union { uint32_t u; float f; } v; v.u = ((uint32_t)b) << 16;
  return v.f;
}
__device__ __forceinline__ void gl_lds16(const void* g, void* l) {
  __builtin_amdgcn_global_load_lds((const __attribute__((address_space(1))) void*)g,
                                   (__attribute__((address_space(3))) void*)l, 16, 0, 0);
}

// ---------------- RMSNorm: x (f32 [4096][2048]) -> xn (bf16) ----------------
__global__ __launch_bounds__(256) void k_rmsnorm(const float* __restrict__ x,
                                                 const float* __restrict__ w,
                                                 u16* __restrict__ xn) {
  int row = blockIdx.x;
  int tid = threadIdx.x;
  const float* xr = x + (size_t)row * HID;
  float4v a = *(const float4v*)(xr + tid * 8);
  float4v b = *(const float4v*)(xr + tid * 8 + 4);
  float s = a[0]*a[0] + a[1]*a[1] + a[2]*a[2] + a[3]*a[3]
          + b[0]*b[0] + b[1]*b[1] + b[2]*b[2] + b[3]*b[3];
  #pragma unroll
  for (int off = 1; off < 64; off <<= 1) s += __shfl_xor(s, off, 64);
  __shared__ float red[4];
  int wv = tid >> 6;
  if ((tid & 63) == 0) red[wv] = s;
  __syncthreads();
  float tot = red[0] + red[1] + red[2] + red[3];
  float r = rsqrtf(tot * (1.0f / HID) + 1e-5f);
  const float* wp = w + tid * 8;
  u16x4 o0, o1;
  #pragma unroll
  for (int j = 0; j < 4; ++j) { o0[j] = f2bf(a[j] * r * wp[j]); o1[j] = f2bf(b[j] * r * wp[4 + j]); }
  *(u16x4*)(xn + (size_t)row * HID + tid * 8) = o0;
  *(u16x4*)(xn + (size_t)row * HID + tid * 8 + 4) = o1;
}

// ---------- weight transpose+convert (all 4): w f32 [K][N] -> wt bf16 [N][K] ----------
__global__ __launch_bounds__(256) void k_wconv4(const float* __restrict__ w0, const float* __restrict__ w1,
                                                const float* __restrict__ w2, const float* __restrict__ w3,
                                                u16* __restrict__ wtbase) {
  int z = blockIdx.z;
  const float* w = (z == 0) ? w0 : (z == 1) ? w1 : (z == 2) ? w2 : w3;
  u16* wt = wtbase + (size_t)z * HID * HID;
  int n0 = blockIdx.x * 64, k0 = blockIdx.y * 64;
  __shared__ float t[64][68];
  int tid = threadIdx.x;
  int cr = tid >> 4;
  int cc = (tid & 15) * 4;
  #pragma unroll
  for (int it = 0; it < 4; ++it) {
    int kk = cr + it * 16;
    float4v v = *(const float4v*)(w + (size_t)(k0 + kk) * HID + n0 + cc);
    t[kk][cc] = v[0]; t[kk][cc + 1] = v[1]; t[kk][cc + 2] = v[2]; t[kk][cc + 3] = v[3];
  }
  __syncthreads();
  #pragma unroll
  for (int it = 0; it < 4; ++it) {
    int nn = cr + it * 16;
    u16x4 o;
    #pragma unroll
    for (int j = 0; j < 4; ++j) o[j] = f2bf(t[cc + j][nn]);
    *(u16x4*)(wt + (size_t)(n0 + nn) * HID + k0 + cc) = o;
  }
}

// ---------- v transpose: vh bf16 [bh][s][d] -> vt bf16 [bh*128+d][s] ----------
__global__ __launch_bounds__(256) void k_vtrans(const u16* __restrict__ v, u16* __restrict__ vt) {
  int s0 = blockIdx.x * 64;
  int d0 = blockIdx.y * 64;
  int bh = blockIdx.z;
  __shared__ u16 t[64][68];
  int tid = threadIdx.x;
  int cr = tid >> 4;
  int cc = (tid & 15) * 4;
  #pragma unroll
  for (int it = 0; it < 4; ++it) {
    int ss = cr + it * 16;
    u16x4 vv = *(const u16x4*)(v + ((size_t)(bh * S_LEN + s0 + ss)) * HD + d0 + cc);
    t[ss][cc] = vv[0]; t[ss][cc + 1] = vv[1]; t[ss][cc + 2] = vv[2]; t[ss][cc + 3] = vv[3];
  }
  __syncthreads();
  #pragma unroll
  for (int it = 0; it < 4; ++it) {
    int dd = cr + it * 16;
    u16x4 o;
    #pragma unroll
    for (int j = 0; j < 4; ++j) o[j] = t[cc + j][dd];
    *(u16x4*)(vt + ((size_t)(bh * HD) + d0 + dd) * S_LEN + s0 + cc) = o;
  }
}

// ---------- RoPE in-place on q and k (head-major [bh][s][d]) ----------
__global__ __launch_bounds__(256) void k_rope(u16* __restrict__ q, u16* __restrict__ k) {
  int gid = blockIdx.x * 256 + threadIdx.x;
  int row = gid >> 6;           // bh*2048 + s, over 65536 rows
  int p = gid & 63;             // pair index
  int s = row & (S_LEN - 1);
  size_t base = (size_t)row * HD;
  float freq = exp2f((float)p * -0.20762050593046014f);  // theta^(-p/64)
  float ang = (float)s * freq;
  float sn, cs;
  sincosf(ang, &sn, &cs);
  {
    float x0 = bf2f(q[base + 2 * p]), x1 = bf2f(q[base + 2 * p + 1]);
    float val = (p & 1) ? (sn * x0 + cs * x1) : (cs * x0 - sn * x1);
    u16 bvv = f2bf(val);
    q[base + p] = bvv; q[base + p + 64] = bvv;
  }
  {
    float x0 = bf2f(k[base + 2 * p]), x1 = bf2f(k[base + 2 * p + 1]);
    float val = (p & 1) ? (sn * x0 + cs * x1) : (cs * x0 - sn * x1);
    u16 bvv = f2bf(val);
    k[base + p] = bvv; k[base + p + 64] = bvv;
  }
}

// ---------- fused QKV GEMM: C[M=4096][N=6144] = A bf16 [M][K] * BT bf16 [N][K] ----------
// outputs head-major: sel-buffer[((b*16+h)*2048 + s)*128 + d]
__global__ __launch_bounds__(256) void k_gemm_qkv(const u16* __restrict__ A, const u16* __restrict__ BT,
                                                  const float* __restrict__ bq, const float* __restrict__ bk,
                                                  const float* __restrict__ bv, u16* __restrict__ qkv) {
  __shared__ __align__(16) u16 lA[128 * 64];
  __shared__ __align__(16) u16 lB[128 * 64];
  int bx = blockIdx.x, by = blockIdx.y;
  int sel = bx >> 4;
  const float* bias = (sel == 0) ? bq : (sel == 1) ? bk : bv;
  u16* outp = qkv + (size_t)sel * NROWS * HID;
  int tid = threadIdx.x;
  int wv = tid >> 6, lane = tid & 63;
  int wr = wv >> 1, wc = wv & 1;
  int lq = lane & 15, lg = lane >> 4;
  f32x4 acc[4][4];
  #pragma unroll
  for (int mi = 0; mi < 4; ++mi)
    #pragma unroll
    for (int ni = 0; ni < 4; ++ni) acc[mi][ni] = (f32x4){0.f, 0.f, 0.f, 0.f};

  const size_t Abase = (size_t)(by * 128) * HID;
  const size_t Bbase = (size_t)(bx * 128) * HID;
  for (int k0 = 0; k0 < HID; k0 += 64) {
    __syncthreads();
    #pragma unroll
    for (int it = 0; it < 4; ++it) {
      int c = it * 256 + tid;
      int row = c >> 3;
      int cir = (c & 7) ^ (row & 7);
      gl_lds16(A + Abase + (size_t)row * HID + k0 + cir * 8, lA + (it * 256 + wv * 64) * 8);
    }
    #pragma unroll
    for (int it = 0; it < 4; ++it) {
      int c = it * 256 + tid;
      int row = c >> 3;
      int cir = (c & 7) ^ (row & 7);
      gl_lds16(BT + Bbase + (size_t)row * HID + k0 + cir * 8, lB + (it * 256 + wv * 64) * 8);
    }
    __syncthreads();
    #pragma unroll
    for (int kk = 0; kk < 2; ++kk) {
      int ch = kk * 4 + lg;
      short8 afr[4], bfr[4];
      #pragma unroll
      for (int mi = 0; mi < 4; ++mi) {
        int r = wr * 64 + mi * 16 + lq;
        afr[mi] = *(const short8*)(lA + r * 64 + ((ch ^ (r & 7)) << 3));
      }
      #pragma unroll
      for (int ni = 0; ni < 4; ++ni) {
        int r = wc * 64 + ni * 16 + lq;
        bfr[ni] = *(const short8*)(lB + r * 64 + ((ch ^ (r & 7)) << 3));
      }
      #pragma unroll
      for (int mi = 0; mi < 4; ++mi)
        #pragma unroll
        for (int ni = 0; ni < 4; ++ni)
          acc[mi][ni] = __builtin_amdgcn_mfma_f32_16x16x32_bf16(afr[mi], bfr[ni], acc[mi][ni], 0, 0, 0);
    }
  }
  #pragma unroll
  for (int ni = 0; ni < 4; ++ni) {
    int colg = bx * 128 + wc * 64 + ni * 16 + lq;
    int col = colg & 2047;
    int h = col >> 7, d = col & 127;
    float bs = bias[col];
    #pragma unroll
    for (int mi = 0; mi < 4; ++mi) {
      #pragma unroll
      for (int r = 0; r < 4; ++r) {
        int rowm = by * 128 + wr * 64 + mi * 16 + lg * 4 + r;
        int b = rowm >> 11, s = rowm & 2047;
        outp[(((size_t)(b * NH + h)) * S_LEN + s) * HD + d] = f2bf(acc[mi][ni][r] + bs);
      }
    }
  }
}

// ---------- output GEMM: C[M=4096][N=2048] f32 = A*BT + bias + resid ----------
__global__ __launch_bounds__(256) void k_gemm_o(const u16* __restrict__ A, const u16* __restrict__ BT,
                                                const float* __restrict__ bias,
                                                const float* __restrict__ resid,
                                                float* __restrict__ outp) {
  __shared__ __align__(16) u16 lA[128 * 64];
  __shared__ __align__(16) u16 lB[128 * 64];
  int bx = blockIdx.x, by = blockIdx.y;
  int tid = threadIdx.x;
  int wv = tid >> 6, lane = tid & 63;
  int wr = wv >> 1, wc = wv & 1;
  int lq = lane & 15, lg = lane >> 4;
  f32x4 acc[4][4];
  #pragma unroll
  for (int mi = 0; mi < 4; ++mi)
    #pragma unroll
    for (int ni = 0; ni < 4; ++ni) acc[mi][ni] = (f32x4){0.f, 0.f, 0.f, 0.f};

  const size_t Abase = (size_t)(by * 128) * HID;
  const size_t Bbase = (size_t)(bx * 128) * HID;
  for (int k0 = 0; k0 < HID; k0 += 64) {
    __syncthreads();
    #pragma unroll
    for (int it = 0; it < 4; ++it) {
      int c = it * 256 + tid;
      int row = c >> 3;
      int cir = (c & 7) ^ (row & 7);
      gl_lds16(A + Abase + (size_t)row * HID + k0 + cir * 8, lA + (it * 256 + wv * 64) * 8);
    }
    #pragma unroll
    for (int it = 0; it < 4; ++it) {
      int c = it * 256 + tid;
      int row = c >> 3;
      int cir = (c & 7) ^ (row & 7);
      gl_lds16(BT + Bbase + (size_t)row * HID + k0 + cir * 8, lB + (it * 256 + wv * 64) * 8);
    }
    __syncthreads();
    #pragma unroll
    for (int kk = 0; kk < 2; ++kk) {
      int ch = kk * 4 + lg;
      short8 afr[4], bfr[4];
      #pragma unroll
      for (int mi = 0; mi < 4; ++mi) {
        int r = wr * 64 + mi * 16 + lq;
        afr[mi] = *(const short8*)(lA + r * 64 + ((ch ^ (r & 7)) << 3));
      }
      #pragma unroll
      for (int ni = 0; ni < 4; ++ni) {
        int r = wc * 64 + ni * 16 + lq;
        bfr[ni] = *(const short8*)(lB + r * 64 + ((ch ^ (r & 7)) << 3));
      }
      #pragma unroll
      for (int mi = 0; mi < 4; ++mi)
        #pragma unroll
        for (int ni = 0; ni < 4; ++ni)
          acc[mi][ni] = __builtin_amdgcn_mfma_f32_16x16x32_bf16(afr[mi], bfr[ni], acc[mi][ni], 0, 0, 0);
    }
  }
  #pragma unroll
  for (int ni = 0; ni < 4; ++ni) {
    int col = bx * 128 + wc * 64 + ni * 16 + lq;
    float bs = bias[col];
    #pragma unroll
    for (int mi = 0; mi < 4; ++mi) {
      #pragma unroll
      for (int r = 0; r < 4; ++r) {
        int rowm = by * 128 + wr * 64 + mi * 16 + lg * 4 + r;
        size_t o = (size_t)rowm * HID + col;
        outp[o] = acc[mi][ni][r] + bs + resid[o];
      }
    }
  }
}

// ---------- flash attention v5: K+V double-buffer, ONE sync per tile (T3 2-phase) ----------
// qh,kh bf16 [bh][s][d] (rope'd head-major), vt bf16 [bh*128+d][s], out bf16 [b][s][h*128+d]
__global__ __launch_bounds__(256) void k_attn(const u16* __restrict__ qh, const u16* __restrict__ kh,
                                              const u16* __restrict__ vt, u16* __restrict__ out) {
  int qt = 31 - blockIdx.x;   // heavy tiles first
  int bh = blockIdx.y;        // b*16+h
  int b = bh >> 4, h = bh & 15;
  int tid = threadIdx.x, wv = tid >> 6, lane = tid & 63;
  int lq = lane & 15, lg = lane >> 4;
  __shared__ __align__(16) u16 Kl[2][64 * 128];
  __shared__ __align__(16) u16 Vl[2][128 * 64];
  __shared__ __align__(16) u16 Pl[4][16 * 72];

  int qrow = qt * 64 + wv * 16 + lq;
  const u16* qb = qh + ((size_t)bh * S_LEN + qrow) * HD;
  short8 qf[4];
  #pragma unroll
  for (int kk = 0; kk < 4; ++kk) qf[kk] = *(const short8*)(qb + kk * 32 + lg * 8);

  f32x4 o[8];
  #pragma unroll
  for (int df = 0; df < 8; ++df) o[df] = (f32x4){0.f, 0.f, 0.f, 0.f};
  float mr = -3.0e38f, l = 0.f;

  const u16* kbase = kh + (size_t)bh * S_LEN * HD;
  const u16* vbase = vt + (size_t)bh * HD * S_LEN;

  int nt = qt + 1;
  // prologue: stage tile 0 into buffers [0]
  #pragma unroll
  for (int it = 0; it < 4; ++it) {
    int c = it * 256 + tid;
    int row = c >> 4;
    int cir = (c & 15) ^ (row & 7);
    gl_lds16(kbase + (size_t)row * HD + cir * 8, Kl[0] + (it * 256 + wv * 64) * 8);
  }
  #pragma unroll
  for (int it = 0; it < 4; ++it) {
    int c = it * 256 + tid;
    int row = c >> 3;
    int cir = (c & 7) ^ (row & 7);
    gl_lds16(vbase + (size_t)row * S_LEN + cir * 8, Vl[0] + (it * 256 + wv * 64) * 8);
  }
  __syncthreads();

  int cur = 0;
  for (int tt = 0; tt < nt; ++tt) {
    // stage tile tt+1 into the other buffers (overlaps with this tile's compute)
    if (tt + 1 < nt) {
      int nxt = cur ^ 1;
      #pragma unroll
      for (int it = 0; it < 4; ++it) {
        int c = it * 256 + tid;
        int row = c >> 4;
        int cir = (c & 15) ^ (row & 7);
        gl_lds16(kbase + ((size_t)((tt + 1) * 64 + row)) * HD + cir * 8,
                 Kl[nxt] + (it * 256 + wv * 64) * 8);
      }
      #pragma unroll
      for (int it = 0; it < 4; ++it) {
        int c = it * 256 + tid;
        int row = c >> 3;
        int cir = (c & 7) ^ (row & 7);
        gl_lds16(vbase + (size_t)row * S_LEN + (tt + 1) * 64 + cir * 8,
                 Vl[nxt] + (it * 256 + wv * 64) * 8);
      }
    }
    const u16* Kc = Kl[cur];
    const u16* Vc = Vl[cur];

    // S^T = K * Q : rows t, cols q (q lane-local)
    f32x4 sa[4];
    #pragma unroll
    for (int mi = 0; mi < 4; ++mi) sa[mi] = (f32x4){0.f, 0.f, 0.f, 0.f};
    __builtin_amdgcn_s_setprio(1);
    #pragma unroll
    for (int kk = 0; kk < 4; ++kk) {
      int ch = kk * 4 + lg;
      #pragma unroll
      for (int mi = 0; mi < 4; ++mi) {
        int tr = mi * 16 + lq;
        short8 a = *(const short8*)(Kc + tr * 128 + ((ch ^ (tr & 7)) << 3));
        sa[mi] = __builtin_amdgcn_mfma_f32_16x16x32_bf16(a, qf[kk], sa[mi], 0, 0, 0);
      }
    }
    __builtin_amdgcn_s_setprio(0);

    // causal mask only on the diagonal tile (wave-uniform branch)
    if (tt == qt) {
      #pragma unroll
      for (int mi = 0; mi < 4; ++mi)
        #pragma unroll
        for (int r = 0; r < 4; ++r) {
          int t = tt * 64 + mi * 16 + lg * 4 + r;
          if (t > qrow) sa[mi][r] = -3.0e38f;
        }
    }
    // tile max
    float vm[4];
    #pragma unroll
    for (int mi = 0; mi < 4; ++mi)
      vm[mi] = fmaxf(fmaxf(sa[mi][0], sa[mi][1]), fmaxf(sa[mi][2], sa[mi][3]));
    float pm = fmaxf(fmaxf(vm[0], vm[1]), fmaxf(vm[2], vm[3]));
    pm = fmaxf(pm, __shfl_xor(pm, 16, 64));
    pm = fmaxf(pm, __shfl_xor(pm, 32, 64));
    // defer-rescale (T13)
    if (!__all(pm <= mr + 64.0f)) {
      float mnew = fmaxf(mr, pm);
      float al = exp2f((mr - mnew) * C2);
      l *= al;
      #pragma unroll
      for (int df = 0; df < 8; ++df) {
        o[df][0] *= al; o[df][1] *= al; o[df][2] *= al; o[df][3] *= al;
      }
      mr = mnew;
    }
    float mc = mr * C2;
    float rs = 0.f;
    #pragma unroll
    for (int mi = 0; mi < 4; ++mi) {
      #pragma unroll
      for (int r = 0; r < 4; ++r) {
        float e = exp2f(fmaf(sa[mi][r], C2, -mc));
        sa[mi][r] = e;
        rs += e;
      }
    }
    rs += __shfl_xor(rs, 16, 64);
    rs += __shfl_xor(rs, 32, 64);
    l += rs;
    // P (bf16) to per-wave LDS (no barrier needed; same-wave read)
    #pragma unroll
    for (int mi = 0; mi < 4; ++mi) {
      u16x4 pk;
      pk[0] = f2bf(sa[mi][0]); pk[1] = f2bf(sa[mi][1]);
      pk[2] = f2bf(sa[mi][2]); pk[3] = f2bf(sa[mi][3]);
      *(u16x4*)(&Pl[wv][lq * 72 + mi * 16 + lg * 4]) = pk;
    }
    // O^T += V^T * P : rows d, cols q
    __builtin_amdgcn_s_setprio(1);
    #pragma unroll
    for (int kk2 = 0; kk2 < 2; ++kk2) {
      short8 pf = *(const short8*)(&Pl[wv][lq * 72 + kk2 * 32 + lg * 8]);
      int ch = kk2 * 4 + lg;
      #pragma unroll
      for (int df = 0; df < 8; ++df) {
        int dr = df * 16 + lq;
        short8 a = *(const short8*)(Vc + dr * 64 + ((ch ^ (dr & 7)) << 3));
        o[df] = __builtin_amdgcn_mfma_f32_16x16x32_bf16(a, pf, o[df], 0, 0, 0);
      }
    }
    __builtin_amdgcn_s_setprio(0);

    // single sync per tile: drains own vmcnt (next tile landed) + barrier (all done with cur)
    __syncthreads();
    cur ^= 1;
  }
  // epilogue: divide by l, store bf16 at [b][qrow][h*128 + d]
  float inv = 1.0f / l;
  size_t ob = (size_t)(b * S_LEN + qrow) * HID + h * HD;
  #pragma unroll
  for (int df = 0; df < 8; ++df) {
    u16x4 pk;
    pk[0] = f2bf(o[df][0] * inv); pk[1] = f2bf(o[df][1] * inv);
    pk[2] = f2bf(o[df][2] * inv); pk[3] = f2bf(o[df][3] * inv);
    *(u16x4*)(out + ob + df * 16 + lg * 4) = pk;
  }
}

extern "C" void kernel_launch(void* const* d_in, const int* in_sizes, int n_in,
                              void* d_out, int out_size, void* d_ws, size_t ws_size,
                              hipStream_t stream) {
  const float* x    = (const float*)d_in[0];
  const float* rmsw = (const float*)d_in[1];
  const float* wq   = (const float*)d_in[2];
  const float* bq   = (const float*)d_in[3];
  const float* wk   = (const float*)d_in[4];
  const float* bk   = (const float*)d_in[5];
  const float* wv   = (const float*)d_in[6];
  const float* bv   = (const float*)d_in[7];
  const float* wo   = (const float*)d_in[8];
  const float* bo   = (const float*)d_in[9];

  char* ws = (char*)d_ws;
  const size_t SZ = (size_t)NROWS * HID * 2;  // bf16 activation bytes
  const size_t WSZ = (size_t)HID * HID * 2;   // bf16 weight bytes
  u16* xn   = (u16*)(ws);
  u16* wqkT = (u16*)(ws + SZ);                // wq|wk|wv|wo transposed, contiguous
  u16* woT  = (u16*)(ws + SZ + 3 * WSZ);
  u16* qhb  = (u16*)(ws + SZ + 4 * WSZ);      // q|k|v head-major, contiguous
  u16* khb  = (u16*)(ws + SZ + 4 * WSZ + SZ);
  u16* vhb  = (u16*)(ws + SZ + 4 * WSZ + 2 * SZ);
  u16* vT   = xn;   // xn dead after QKV GEMM
  u16* ao   = vhb;  // vh dead after transpose

  k_rmsnorm<<<dim3(NROWS), dim3(256), 0, stream>>>(x, rmsw, xn);
  k_wconv4<<<dim3(32, 32, 4), dim3(256), 0, stream>>>(wq, wk, wv, wo, wqkT);
  k_gemm_qkv<<<dim3(48, 32), dim3(256), 0, stream>>>(xn, wqkT, bq, bk, bv, qhb);
  k_rope<<<dim3(16384), dim3(256), 0, stream>>>(qhb, khb);
  k_vtrans<<<dim3(32, 2, 32), dim3(256), 0, stream>>>(vhb, vT);
  k_attn<<<dim3(32, 32), dim3(256), 0, stream>>>(qhb, khb, vT, ao);
  k_gemm_o<<<dim3(16, 32), dim3(256), 0, stream>>>(ao, woT, bo, x, (float*)d_out);
}